// Round 16
// baseline (1048.308 us; speedup 1.0000x reference)
//
#include <hip/hip_runtime.h>

#define NEG_SLOPE 0.01f
#define GN_EPS 1e-5f

typedef __attribute__((ext_vector_type(8))) __bf16 bf16x8;
typedef __attribute__((ext_vector_type(4))) __bf16 bf16x4;
typedef __attribute__((ext_vector_type(4))) float f32x4;
typedef __attribute__((ext_vector_type(4))) unsigned uintx4;

__device__ __forceinline__ float bf_lo(unsigned v) { return __uint_as_float(v << 16); }
__device__ __forceinline__ float bf_hi(unsigned v) { return __uint_as_float(v & 0xffff0000u); }

// ===========================================================================
// CSR build: histogram -> 2-level exclusive scan -> inverse-permutation
// scatter. scatter writes inv[e] sequentially in e (coalesced) — r11 showed
// permuted-position payload scatter costs 155us in write-allocate traffic.
// ===========================================================================
__global__ __launch_bounds__(256) void hist_kernel(
    const int* __restrict__ om, int* __restrict__ cnt, int E)
{
    const int stride = gridDim.x * blockDim.x;
    for (int e = blockIdx.x * blockDim.x + threadIdx.x; e < E; e += stride)
        atomicAdd(&cnt[om[e]], 1);
}

__global__ __launch_bounds__(256) void scan1_kernel(
    const int* __restrict__ cnt, int* __restrict__ part, int N)
{
    __shared__ int ls[256];
    int b = blockIdx.x, t = threadIdx.x;
    int i0 = b * 1024 + t * 4, s = 0;
#pragma unroll
    for (int u = 0; u < 4; ++u) if (i0 + u < N) s += cnt[i0 + u];
    ls[t] = s; __syncthreads();
    for (int off = 128; off > 0; off >>= 1) {
        if (t < off) ls[t] += ls[t + off];
        __syncthreads();
    }
    if (t == 0) part[b] = ls[0];
}

__global__ void scan2_kernel(int* __restrict__ part, int nb)
{
    if (blockIdx.x == 0 && threadIdx.x == 0) {
        int run = 0;
        for (int i = 0; i < nb; ++i) { int v = part[i]; part[i] = run; run += v; }
    }
}

__global__ __launch_bounds__(256) void scan3_kernel(
    const int* __restrict__ cnt, const int* __restrict__ part,
    int* __restrict__ base, int N)
{
    __shared__ int ls[256];
    int b = blockIdx.x, t = threadIdx.x;
    int i0 = b * 1024 + t * 4;
    int v0 = 0, v1 = 0, v2 = 0, v3 = 0;
    if (i0 + 0 < N) v0 = cnt[i0 + 0];
    if (i0 + 1 < N) v1 = cnt[i0 + 1];
    if (i0 + 2 < N) v2 = cnt[i0 + 2];
    if (i0 + 3 < N) v3 = cnt[i0 + 3];
    int s = v0 + v1 + v2 + v3;
    ls[t] = s; __syncthreads();
    for (int off = 1; off < 256; off <<= 1) {
        int x = (t >= off) ? ls[t - off] : 0;
        __syncthreads();
        ls[t] += x;
        __syncthreads();
    }
    int run = part[b] + ls[t] - s;   // exclusive prefix
    if (i0 + 0 < N) { base[i0 + 0] = run; run += v0; if (i0 + 0 == N - 1) base[N] = run; }
    if (i0 + 1 < N) { base[i0 + 1] = run; run += v1; if (i0 + 1 == N - 1) base[N] = run; }
    if (i0 + 2 < N) { base[i0 + 2] = run; run += v2; if (i0 + 2 == N - 1) base[N] = run; }
    if (i0 + 3 < N) { base[i0 + 3] = run; run += v3; if (i0 + 3 == N - 1) base[N] = run; }
}

__global__ __launch_bounds__(256) void scatter_kernel(
    const int* __restrict__ om, const int* __restrict__ base,
    int* __restrict__ cur, int* __restrict__ inv, int E)
{
    const int stride = gridDim.x * blockDim.x;
    for (int e = blockIdx.x * blockDim.x + threadIdx.x; e < E; e += stride) {
        int o = om[e];
        int p = base[o] + atomicAdd(&cur[o], 1);
        inv[e] = p;           // edge e's C row lands at o-sorted position p
    }
}

// ===========================================================================
// Phase A: per-offset GEMM via bf16 MFMA (r7 orientation: D row=edge,
// col=channel; lane-quarter emits each row as 4 consecutive 32B pieces ->
// write-combine merges to full lines, WRITE_SIZE == |C|). C row for edge e
// goes to sorted position inv[e]; non-temporal stores (read once by reduce).
// NORM (bf16 path only): gather applies GroupNorm scale/shift (stats from
// the preceding reduce) in-register -> mid-residual y never materialized.
// r9 proved the numerics; r9's cost was the fp32 gather (FETCH 2x), which a
// bf16 accumulator eliminates.
// ===========================================================================
template<int F32IN, int NORM>
__global__ __launch_bounds__(256) void conv_mfma_kernel(
    const void* __restrict__ feats, const float* __restrict__ W,
    const int* __restrict__ in_map, const int* __restrict__ inv,
    __bf16* __restrict__ C, int M, int BPK,
    const float* __restrict__ stats, const float* __restrict__ gamma,
    const float* __restrict__ beta, float invc)
{
    const int lane = threadIdx.x & 63;
    const int wv   = threadIdx.x >> 6;
    const int k    = blockIdx.x / BPK;
    const int blk  = blockIdx.x % BPK;
    const int l15  = lane & 15;
    const int lg   = lane >> 4;         // 0..3

    // per-lane GN scale/shift for its 16 gather channels {hh*32+lg*8+j}
    float scv[2][8], shv[2][8];
    if (NORM) {
#pragma unroll
        for (int hh = 0; hh < 2; ++hh) {
            int g = hh * 4 + lg;
            float mean = stats[g] * invc;
            float var  = fmaf(-mean, mean, stats[8 + g] * invc);
            float rstd = rsqrtf(var + GN_EPS);
#pragma unroll
            for (int j = 0; j < 8; ++j) {
                int ch = hh * 32 + lg * 8 + j;
                float s = rstd * gamma[ch];
                scv[hh][j] = s;
                shv[hh][j] = fmaf(-mean, s, beta[ch]);
            }
        }
    }

    // B fragments: b[nt][h] covers cols nt*16+l15, K-half h
    const float* Wk = W + (size_t)k * 4096;
    bf16x8 b[4][2];
#pragma unroll
    for (int nt = 0; nt < 4; ++nt)
#pragma unroll
        for (int h = 0; h < 2; ++h)
#pragma unroll
            for (int j = 0; j < 8; ++j)
                b[nt][h][j] = (__bf16)Wk[(h * 32 + lg * 8 + j) * 64 + nt * 16 + l15];

    const int* imk   = in_map + (size_t)k * M;
    const int ntiles = (M + 15) >> 4;
    const int wpk    = BPK * 4;

    for (int t = blk * 4 + wv; t < ntiles; t += wpk) {
        int m  = t * 16 + l15;
        int mc = m < M ? m : M - 1;
        int ii = imk[mc];
        bf16x8 a0, a1;
        if (F32IN) {
            const float4* rp = (const float4*)((const float*)feats + (size_t)ii * 64 + lg * 8);
            float4 u0 = rp[0], u1 = rp[1];
            float4 u2 = rp[8], u3 = rp[9];   // +32 channels
            a0[0] = (__bf16)u0.x; a0[1] = (__bf16)u0.y; a0[2] = (__bf16)u0.z; a0[3] = (__bf16)u0.w;
            a0[4] = (__bf16)u1.x; a0[5] = (__bf16)u1.y; a0[6] = (__bf16)u1.z; a0[7] = (__bf16)u1.w;
            a1[0] = (__bf16)u2.x; a1[1] = (__bf16)u2.y; a1[2] = (__bf16)u2.z; a1[3] = (__bf16)u2.w;
            a1[4] = (__bf16)u3.x; a1[5] = (__bf16)u3.y; a1[6] = (__bf16)u3.z; a1[7] = (__bf16)u3.w;
        } else {
            const bf16x8* rp = (const bf16x8*)((const __bf16*)feats + (size_t)ii * 64 + lg * 8);
            if (NORM) {
                bf16x8 r0 = rp[0], r1 = rp[4];
#pragma unroll
                for (int j = 0; j < 8; ++j) {
                    float v0 = fmaf((float)r0[j], scv[0][j], shv[0][j]);
                    float v1 = fmaf((float)r1[j], scv[1][j], shv[1][j]);
                    a0[j] = (__bf16)v0;
                    a1[j] = (__bf16)v1;
                }
            } else {
                a0 = rp[0];
                a1 = rp[4];   // +32 channels
            }
        }
        f32x4 c0 = {0.f,0.f,0.f,0.f}, c1 = c0, c2 = c0, c3 = c0;
        c0 = __builtin_amdgcn_mfma_f32_16x16x32_bf16(a0, b[0][0], c0, 0, 0, 0);
        c1 = __builtin_amdgcn_mfma_f32_16x16x32_bf16(a0, b[1][0], c1, 0, 0, 0);
        c2 = __builtin_amdgcn_mfma_f32_16x16x32_bf16(a0, b[2][0], c2, 0, 0, 0);
        c3 = __builtin_amdgcn_mfma_f32_16x16x32_bf16(a0, b[3][0], c3, 0, 0, 0);
        c0 = __builtin_amdgcn_mfma_f32_16x16x32_bf16(a1, b[0][1], c0, 0, 0, 0);
        c1 = __builtin_amdgcn_mfma_f32_16x16x32_bf16(a1, b[1][1], c1, 0, 0, 0);
        c2 = __builtin_amdgcn_mfma_f32_16x16x32_bf16(a1, b[2][1], c2, 0, 0, 0);
        c3 = __builtin_amdgcn_mfma_f32_16x16x32_bf16(a1, b[3][1], c3, 0, 0, 0);

        const int e_base = k * M + t * 16;
        f32x4 cc[4] = {c0, c1, c2, c3};
#pragma unroll
        for (int r = 0; r < 4; ++r) {
            int row = lg * 4 + r;
            if (t * 16 + row < M) {
                int p = inv[e_base + row];            // broadcast within l15-group
                __bf16* cr = C + (size_t)p * 64 + l15;
#pragma unroll
                for (int nt = 0; nt < 4; ++nt) {
                    __bf16 v = (__bf16)cc[nt][r];
                    __builtin_nontemporal_store(v, cr + nt * 16);
                }
            }
        }
    }
}

// ===========================================================================
// Phase B: segmented streaming reduce + FUSED GroupNorm stats. One wave per
// output row per iter; 8 rows/instruction: lane = (row l>>3) x (channel
// octet l&7), dwordx4 load = 1KB/wave-instruction. Channel octet == GN
// group. Output is bf16 (19MB).
// ===========================================================================
__global__ __launch_bounds__(256) void reduce_kernel(
    const uintx4* __restrict__ C4, const int* __restrict__ base,
    __bf16* __restrict__ out, float* __restrict__ stats, int N)
{
    const int lane = threadIdx.x & 63;
    const int wv   = threadIdx.x >> 6;
    const int ro   = lane >> 3;       // row offset 0..7
    const int oc   = lane & 7;        // channel octet == GN group
    float rs = 0.f, rq = 0.f;

    const int ostride = gridDim.x * 4;
    for (int o = blockIdx.x * 4 + wv; o < N; o += ostride) {
        const int s = base[o], t = base[o + 1];
        float a0 = 0.f, a1 = 0.f, a2 = 0.f, a3 = 0.f;
        float a4 = 0.f, a5 = 0.f, a6 = 0.f, a7 = 0.f;
        for (int i = s + ro; i < t; i += 8) {
            uintx4 v = __builtin_nontemporal_load(&C4[(size_t)i * 8 + oc]);
            a0 += bf_lo(v.x); a1 += bf_hi(v.x);
            a2 += bf_lo(v.y); a3 += bf_hi(v.y);
            a4 += bf_lo(v.z); a5 += bf_hi(v.z);
            a6 += bf_lo(v.w); a7 += bf_hi(v.w);
        }
#pragma unroll
        for (int m = 8; m <= 32; m <<= 1) {
            a0 += __shfl_xor(a0, m); a1 += __shfl_xor(a1, m);
            a2 += __shfl_xor(a2, m); a3 += __shfl_xor(a3, m);
            a4 += __shfl_xor(a4, m); a5 += __shfl_xor(a5, m);
            a6 += __shfl_xor(a6, m); a7 += __shfl_xor(a7, m);
        }
        if (ro == 0) {
            bf16x8 r;
            r[0] = (__bf16)a0; r[1] = (__bf16)a1; r[2] = (__bf16)a2; r[3] = (__bf16)a3;
            r[4] = (__bf16)a4; r[5] = (__bf16)a5; r[6] = (__bf16)a6; r[7] = (__bf16)a7;
            *(bf16x8*)(out + (size_t)o * 64 + oc * 8) = r;
            rs += ((a0 + a1) + (a2 + a3)) + ((a4 + a5) + (a6 + a7));
            rq += ((a0*a0 + a1*a1) + (a2*a2 + a3*a3)) + ((a4*a4 + a5*a5) + (a6*a6 + a7*a7));
        }
    }
    __shared__ float ls[4][16];
    if (ro == 0) { ls[wv][oc] = rs; ls[wv][8 + oc] = rq; }
    __syncthreads();
    if (threadIdx.x < 16) {
        float t = (ls[0][threadIdx.x] + ls[1][threadIdx.x]) +
                  (ls[2][threadIdx.x] + ls[3][threadIdx.x]);
        unsafeAtomicAdd(stats + threadIdx.x, t);
    }
}

// ===========================================================================
// GroupNorm apply (+residual, +leaky); BFIN: input is bf16 (main path) or
// fp32 (fallback). fp32 and/or bf16 outputs.
// ===========================================================================
template<int BFIN>
__global__ __launch_bounds__(256) void gn_apply_kernel(
    const void* __restrict__ xin, const float* __restrict__ stats,
    const float* __restrict__ gamma, const float* __restrict__ beta,
    const float4* resid, float4* out_f, bf16x4* out_bf,
    long total4, float invc, int do_leaky)
{
    __shared__ float sc[64], sh[64];
    if (threadIdx.x < 64) {
        int c = threadIdx.x, g = c >> 3;
        float mean = stats[g] * invc;
        float var  = fmaf(-mean, mean, stats[8 + g] * invc);
        float s    = rsqrtf(var + GN_EPS) * gamma[c];
        sc[c] = s;
        sh[c] = fmaf(-mean, s, beta[c]);
    }
    __syncthreads();
    const long stride = (long)gridDim.x * blockDim.x;
    for (long i = (long)blockIdx.x * blockDim.x + threadIdx.x; i < total4; i += stride) {
        float4 v;
        if (BFIN) {
            bf16x4 u = ((const bf16x4*)xin)[i];
            v.x = (float)u.x; v.y = (float)u.y; v.z = (float)u.z; v.w = (float)u.w;
        } else {
            v = ((const float4*)xin)[i];
        }
        int c0 = ((int)(i & 15)) << 2;
        float4 r;
        r.x = fmaf(v.x, sc[c0 + 0], sh[c0 + 0]);
        r.y = fmaf(v.y, sc[c0 + 1], sh[c0 + 1]);
        r.z = fmaf(v.z, sc[c0 + 2], sh[c0 + 2]);
        r.w = fmaf(v.w, sc[c0 + 3], sh[c0 + 3]);
        if (resid) {
            float4 h4 = resid[i];
            r.x += h4.x; r.y += h4.y; r.z += h4.z; r.w += h4.w;
        }
        if (do_leaky) {
            r.x = r.x >= 0.f ? r.x : NEG_SLOPE * r.x;
            r.y = r.y >= 0.f ? r.y : NEG_SLOPE * r.y;
            r.z = r.z >= 0.f ? r.z : NEG_SLOPE * r.z;
            r.w = r.w >= 0.f ? r.w : NEG_SLOPE * r.w;
        }
        if (out_f) out_f[i] = r;
        if (out_bf) {
            bf16x4 o;
            o.x = (__bf16)r.x; o.y = (__bf16)r.y; o.z = (__bf16)r.z; o.w = (__bf16)r.w;
            out_bf[i] = o;
        }
    }
}

// ===========================================================================
// Legacy atomic-scatter conv + standalone gn_stats (ws_size fallback path)
// ===========================================================================
__global__ __launch_bounds__(256) void conv_kernel(
    const float* __restrict__ feats, const float* __restrict__ W,
    const int* __restrict__ in_map, const int* __restrict__ out_map,
    float* __restrict__ out, int M, int BPK)
{
    const int lane = threadIdx.x & 63;
    const int wv   = threadIdx.x >> 6;
    const int k    = blockIdx.x / BPK;
    const int blk  = blockIdx.x % BPK;
    const float* Wk = W + (size_t)k * 4096;
    float w[64];
#pragma unroll
    for (int c = 0; c < 64; ++c) w[c] = Wk[c * 64 + lane];
    __shared__ float fbuf[4][64];
    const int* im = in_map + (size_t)k * M;
    const int* om = out_map + (size_t)k * M;
    const int stride = BPK * 4;
    for (int m = blk * 4 + wv; m < M; m += stride) {
        int ii = im[m];
        int oi = om[m];
        float f = feats[(size_t)ii * 64 + lane];
        fbuf[wv][lane] = f;
        const float* fb = fbuf[wv];
        float a0 = 0.f, a1 = 0.f, a2 = 0.f, a3 = 0.f;
#pragma unroll
        for (int c = 0; c < 64; c += 4) {
            float4 f4 = *(const float4*)(fb + c);
            a0 = fmaf(f4.x, w[c + 0], a0);
            a1 = fmaf(f4.y, w[c + 1], a1);
            a2 = fmaf(f4.z, w[c + 2], a2);
            a3 = fmaf(f4.w, w[c + 3], a3);
        }
        unsafeAtomicAdd(out + (size_t)oi * 64 + lane, (a0 + a1) + (a2 + a3));
    }
}

__global__ __launch_bounds__(256) void gn_stats_kernel(
    const float4* __restrict__ x, float* __restrict__ stats, long total4)
{
    const int lane = threadIdx.x & 63;
    float s = 0.f, q = 0.f;
    const long stride = (long)gridDim.x * blockDim.x;
    for (long i = (long)blockIdx.x * blockDim.x + threadIdx.x; i < total4; i += stride) {
        float4 v = x[i];
        s += (v.x + v.y) + (v.z + v.w);
        q += (v.x * v.x + v.y * v.y) + (v.z * v.z + v.w * v.w);
    }
    s += __shfl_xor(s, 1);  q += __shfl_xor(q, 1);
    s += __shfl_xor(s, 16); q += __shfl_xor(q, 16);
    s += __shfl_xor(s, 32); q += __shfl_xor(q, 32);
    __shared__ float ls[4][16];
    const int wv = threadIdx.x >> 6;
    const int g = (lane >> 1) & 7;
    if (lane < 16 && (lane & 1) == 0) { ls[wv][g] = s; ls[wv][8 + g] = q; }
    __syncthreads();
    if (threadIdx.x < 16) {
        float t = (ls[0][threadIdx.x] + ls[1][threadIdx.x]) +
                  (ls[2][threadIdx.x] + ls[3][threadIdx.x]);
        unsafeAtomicAdd(stats + threadIdx.x, t);
    }
}

// ===========================================================================
extern "C" void kernel_launch(void* const* d_in, const int* in_sizes, int n_in,
                              void* d_out, int out_size, void* d_ws, size_t ws_size,
                              hipStream_t stream) {
    const float* x   = (const float*)d_in[0];
    const float* W1  = (const float*)d_in[1];
    const float* g1  = (const float*)d_in[2];
    const float* b1  = (const float*)d_in[3];
    const float* Wa1 = (const float*)d_in[4];
    const float* ga1 = (const float*)d_in[5];
    const float* ba1 = (const float*)d_in[6];
    const float* Wb1 = (const float*)d_in[7];
    const float* gb1 = (const float*)d_in[8];
    const float* bb1 = (const float*)d_in[9];
    const float* Wa2 = (const float*)d_in[10];
    const float* ga2 = (const float*)d_in[11];
    const float* ba2 = (const float*)d_in[12];
    const float* Wb2 = (const float*)d_in[13];
    const float* gb2 = (const float*)d_in[14];
    const float* bb2 = (const float*)d_in[15];
    const int* m1_in  = (const int*)d_in[16];
    const int* m1_out = (const int*)d_in[17];
    const int* m2_in  = (const int*)d_in[18];
    const int* m2_out = (const int*)d_in[19];

    const int N   = out_size / 64;
    const int M1  = in_sizes[16] / 8;
    const int M2  = in_sizes[18] / 27;
    const int E1  = 8 * M1;
    const int E2  = 27 * M2;
    const int Emax = E1 > E2 ? E1 : E2;

    float* h = (float*)d_out;
    const long  total4 = (long)N * 16;
    const float invc   = 1.f / ((float)N * 8.f);

    // ---- workspace layout (256B aligned) ----
    char* wp = (char*)d_ws;
    size_t off = 0;
    auto alloc = [&](size_t bytes) {
        void* p = wp + off;
        off = (off + bytes + 255) & ~(size_t)255;
        return p;
    };
    __bf16* accbf = (__bf16*)alloc((size_t)N * 64 * 2);
    __bf16* hbf   = (__bf16*)alloc((size_t)N * 64 * 2);
    __bf16* Cbuf  = (__bf16*)alloc((size_t)Emax * 64 * 2);
    int*    base1 = (int*)alloc((size_t)(N + 1) * 4);
    int*    base2 = (int*)alloc((size_t)(N + 1) * 4);
    int*    cnt   = (int*)alloc((size_t)N * 4);
    int*    part  = (int*)alloc(4096);
    int*    inv1  = (int*)alloc((size_t)E1 * 4);
    int*    inv2  = (int*)alloc((size_t)E2 * 4);
    float*  stats = (float*)alloc(5 * 16 * 4);   // st0, stA1, stB1, stA2, stB2
    const size_t need = off;

    if (ws_size < need) {
        // -------- legacy atomic fallback (independent fp32 layout) --------
        float* accF = (float*)d_ws;
        float* yF   = accF + (size_t)N * 64;
        float* stF  = yF + (size_t)N * 64;
        const size_t nbytes = (size_t)N * 64 * 4;
        auto convL = [&](const float* feats, const float* W, const int* im,
                         const int* om, int K, int M, int BPK) {
            hipMemsetAsync(accF, 0, nbytes, stream);
            conv_kernel<<<dim3(K * BPK), 256, 0, stream>>>(feats, W, im, om, accF, M, BPK);
        };
        auto gnL = [&](const float* gamma, const float* beta, const float* resid,
                       float* outp, int leaky) {
            hipMemsetAsync(stF, 0, 16 * sizeof(float), stream);
            gn_stats_kernel<<<1024, 256, 0, stream>>>((const float4*)accF, stF, total4);
            gn_apply_kernel<0><<<1024, 256, 0, stream>>>(accF, stF, gamma, beta,
                                                         (const float4*)resid, (float4*)outp,
                                                         nullptr, total4, invc, leaky);
        };
        convL(x, W1, m1_in, m1_out, 8, M1, 320); gnL(g1, b1, nullptr, h, 1);
        convL(h, Wa1, m2_in, m2_out, 27, M2, 96); gnL(ga1, ba1, nullptr, yF, 0);
        convL(yF, Wb1, m2_in, m2_out, 27, M2, 96); gnL(gb1, bb1, h, h, 1);
        convL(h, Wa2, m2_in, m2_out, 27, M2, 96); gnL(ga2, ba2, nullptr, yF, 0);
        convL(yF, Wb2, m2_in, m2_out, 27, M2, 96); gnL(gb2, bb2, h, h, 1);
        return;
    }

    // -------- MFMA + sorted-streaming-reduce + fused-mid-GN path --------
    hipMemsetAsync(stats, 0, 5 * 16 * sizeof(float), stream);

    const int nb = (N + 1023) / 1024;
    auto buildCSR = [&](const int* om, int E, int* base, int* inv) {
        hipMemsetAsync(cnt, 0, (size_t)N * 4, stream);
        hist_kernel<<<2048, 256, 0, stream>>>(om, cnt, E);
        scan1_kernel<<<nb, 256, 0, stream>>>(cnt, part, N);
        scan2_kernel<<<1, 64, 0, stream>>>(part, nb);
        scan3_kernel<<<nb, 256, 0, stream>>>(cnt, part, base, N);
        hipMemsetAsync(cnt, 0, (size_t)N * 4, stream);
        scatter_kernel<<<2048, 256, 0, stream>>>(om, base, cnt, inv, E);
    };
    buildCSR(m1_out, E1, base1, inv1);
    buildCSR(m2_out, E2, base2, inv2);

    float* st0  = stats;
    float* stA1 = stats + 16;
    float* stB1 = stats + 32;
    float* stA2 = stats + 48;
    float* stB2 = stats + 64;

    // variant 0: bf16 gather; 1: fp32 gather; 2: bf16 gather + fused GN
    auto conv = [&](const void* feats, int variant, const float* W, const int* im,
                    int K, int M, int BPK, const int* base, const int* inv,
                    float* statOut, const float* nst, const float* ngm,
                    const float* nbt) {
        dim3 grid(K * BPK);
        if (variant == 2)
            conv_mfma_kernel<0, 1><<<grid, 256, 0, stream>>>(feats, W, im, inv, Cbuf,
                M, BPK, nst, ngm, nbt, invc);
        else if (variant == 1)
            conv_mfma_kernel<1, 0><<<grid, 256, 0, stream>>>(feats, W, im, inv, Cbuf,
                M, BPK, nullptr, nullptr, nullptr, invc);
        else
            conv_mfma_kernel<0, 0><<<grid, 256, 0, stream>>>(feats, W, im, inv, Cbuf,
                M, BPK, nullptr, nullptr, nullptr, invc);
        reduce_kernel<<<2048, 256, 0, stream>>>((const uintx4*)Cbuf, base,
                                                accbf, statOut, N);
    };
    auto gn = [&](const float* st, const float* gamma, const float* beta,
                  const float* resid, float* outf, __bf16* outbf, int leaky) {
        gn_apply_kernel<1><<<2048, 256, 0, stream>>>(accbf, st, gamma, beta,
                                                     (const float4*)resid, (float4*)outf,
                                                     (bf16x4*)outbf, total4, invc, leaky);
    };

    // BasicConvolutionBlock (gathers fp32 x directly)
    conv(x, 1, W1, m1_in, 8, M1, 256, base1, inv1, st0, nullptr, nullptr, nullptr);
    gn(st0, g1, b1, nullptr, h, hbf, 1);
    // ResidualBlock 1: y = GN(conv_a) applied inside conv_b's gather
    conv(hbf, 0, Wa1, m2_in, 27, M2, 96, base2, inv2, stA1, nullptr, nullptr, nullptr);
    conv(accbf, 2, Wb1, m2_in, 27, M2, 96, base2, inv2, stB1, stA1, ga1, ba1);
    gn(stB1, gb1, bb1, h, h, hbf, 1);
    // ResidualBlock 2
    conv(hbf, 0, Wa2, m2_in, 27, M2, 96, base2, inv2, stA2, nullptr, nullptr, nullptr);
    conv(accbf, 2, Wb2, m2_in, 27, M2, 96, base2, inv2, stB2, stA2, ga2, ba2);
    gn(stB2, gb2, bb2, h, h, nullptr, 1);
}

// Round 17
// 1015.926 us; speedup vs baseline: 1.0319x; 1.0319x over previous
//
#include <hip/hip_runtime.h>

#define NEG_SLOPE 0.01f
#define GN_EPS 1e-5f

typedef __attribute__((ext_vector_type(8))) __bf16 bf16x8;
typedef __attribute__((ext_vector_type(4))) __bf16 bf16x4;
typedef __attribute__((ext_vector_type(4))) float f32x4;
typedef __attribute__((ext_vector_type(4))) unsigned uintx4;

__device__ __forceinline__ float bf_lo(unsigned v) { return __uint_as_float(v << 16); }
__device__ __forceinline__ float bf_hi(unsigned v) { return __uint_as_float(v & 0xffff0000u); }

// ===========================================================================
// CSR build: histogram -> 2-level exclusive scan -> inverse-permutation
// scatter. scatter writes inv[e] sequentially in e (coalesced) — r11 showed
// permuted-position payload scatter costs 155us in write-allocate traffic.
// ===========================================================================
__global__ __launch_bounds__(256) void hist_kernel(
    const int* __restrict__ om, int* __restrict__ cnt, int E)
{
    const int stride = gridDim.x * blockDim.x;
    for (int e = blockIdx.x * blockDim.x + threadIdx.x; e < E; e += stride)
        atomicAdd(&cnt[om[e]], 1);
}

__global__ __launch_bounds__(256) void scan1_kernel(
    const int* __restrict__ cnt, int* __restrict__ part, int N)
{
    __shared__ int ls[256];
    int b = blockIdx.x, t = threadIdx.x;
    int i0 = b * 1024 + t * 4, s = 0;
#pragma unroll
    for (int u = 0; u < 4; ++u) if (i0 + u < N) s += cnt[i0 + u];
    ls[t] = s; __syncthreads();
    for (int off = 128; off > 0; off >>= 1) {
        if (t < off) ls[t] += ls[t + off];
        __syncthreads();
    }
    if (t == 0) part[b] = ls[0];
}

__global__ void scan2_kernel(int* __restrict__ part, int nb)
{
    if (blockIdx.x == 0 && threadIdx.x == 0) {
        int run = 0;
        for (int i = 0; i < nb; ++i) { int v = part[i]; part[i] = run; run += v; }
    }
}

__global__ __launch_bounds__(256) void scan3_kernel(
    const int* __restrict__ cnt, const int* __restrict__ part,
    int* __restrict__ base, int N)
{
    __shared__ int ls[256];
    int b = blockIdx.x, t = threadIdx.x;
    int i0 = b * 1024 + t * 4;
    int v0 = 0, v1 = 0, v2 = 0, v3 = 0;
    if (i0 + 0 < N) v0 = cnt[i0 + 0];
    if (i0 + 1 < N) v1 = cnt[i0 + 1];
    if (i0 + 2 < N) v2 = cnt[i0 + 2];
    if (i0 + 3 < N) v3 = cnt[i0 + 3];
    int s = v0 + v1 + v2 + v3;
    ls[t] = s; __syncthreads();
    for (int off = 1; off < 256; off <<= 1) {
        int x = (t >= off) ? ls[t - off] : 0;
        __syncthreads();
        ls[t] += x;
        __syncthreads();
    }
    int run = part[b] + ls[t] - s;   // exclusive prefix
    if (i0 + 0 < N) { base[i0 + 0] = run; run += v0; if (i0 + 0 == N - 1) base[N] = run; }
    if (i0 + 1 < N) { base[i0 + 1] = run; run += v1; if (i0 + 1 == N - 1) base[N] = run; }
    if (i0 + 2 < N) { base[i0 + 2] = run; run += v2; if (i0 + 2 == N - 1) base[N] = run; }
    if (i0 + 3 < N) { base[i0 + 3] = run; run += v3; if (i0 + 3 == N - 1) base[N] = run; }
}

__global__ __launch_bounds__(256) void scatter_kernel(
    const int* __restrict__ om, const int* __restrict__ base,
    int* __restrict__ cur, int* __restrict__ inv, int E)
{
    const int stride = gridDim.x * blockDim.x;
    for (int e = blockIdx.x * blockDim.x + threadIdx.x; e < E; e += stride) {
        int o = om[e];
        int p = base[o] + atomicAdd(&cur[o], 1);
        inv[e] = p;           // edge e's C row lands at o-sorted position p
    }
}

// ===========================================================================
// Phase A: per-offset GEMM via bf16 MFMA (r7 orientation: D row=edge,
// col=channel; lane-quarter emits each row as 4 consecutive 32B pieces ->
// write-combine merges to full lines, WRITE_SIZE == |C|). C row for edge e
// goes to sorted position inv[e]; non-temporal (read once by reduce).
// ===========================================================================
template<int F32IN>
__global__ __launch_bounds__(256) void conv_mfma_kernel(
    const void* __restrict__ feats, const float* __restrict__ W,
    const int* __restrict__ in_map, const int* __restrict__ inv,
    __bf16* __restrict__ C, int M, int BPK)
{
    const int lane = threadIdx.x & 63;
    const int wv   = threadIdx.x >> 6;
    const int k    = blockIdx.x / BPK;
    const int blk  = blockIdx.x % BPK;
    const int l15  = lane & 15;
    const int lg   = lane >> 4;         // 0..3

    // B fragments: b[nt][h] covers cols nt*16+l15, K-half h
    const float* Wk = W + (size_t)k * 4096;
    bf16x8 b[4][2];
#pragma unroll
    for (int nt = 0; nt < 4; ++nt)
#pragma unroll
        for (int h = 0; h < 2; ++h)
#pragma unroll
            for (int j = 0; j < 8; ++j)
                b[nt][h][j] = (__bf16)Wk[(h * 32 + lg * 8 + j) * 64 + nt * 16 + l15];

    const int* imk   = in_map + (size_t)k * M;
    const int ntiles = (M + 15) >> 4;
    const int wpk    = BPK * 4;

    for (int t = blk * 4 + wv; t < ntiles; t += wpk) {
        int m  = t * 16 + l15;
        int mc = m < M ? m : M - 1;
        int ii = imk[mc];
        bf16x8 a0, a1;
        if (F32IN) {
            const float4* rp = (const float4*)((const float*)feats + (size_t)ii * 64 + lg * 8);
            float4 u0 = rp[0], u1 = rp[1];
            float4 u2 = rp[8], u3 = rp[9];   // +32 channels
            a0[0] = (__bf16)u0.x; a0[1] = (__bf16)u0.y; a0[2] = (__bf16)u0.z; a0[3] = (__bf16)u0.w;
            a0[4] = (__bf16)u1.x; a0[5] = (__bf16)u1.y; a0[6] = (__bf16)u1.z; a0[7] = (__bf16)u1.w;
            a1[0] = (__bf16)u2.x; a1[1] = (__bf16)u2.y; a1[2] = (__bf16)u2.z; a1[3] = (__bf16)u2.w;
            a1[4] = (__bf16)u3.x; a1[5] = (__bf16)u3.y; a1[6] = (__bf16)u3.z; a1[7] = (__bf16)u3.w;
        } else {
            const bf16x8* rp = (const bf16x8*)((const __bf16*)feats + (size_t)ii * 64 + lg * 8);
            a0 = rp[0];
            a1 = rp[4];   // +32 channels
        }
        f32x4 c0 = {0.f,0.f,0.f,0.f}, c1 = c0, c2 = c0, c3 = c0;
        c0 = __builtin_amdgcn_mfma_f32_16x16x32_bf16(a0, b[0][0], c0, 0, 0, 0);
        c1 = __builtin_amdgcn_mfma_f32_16x16x32_bf16(a0, b[1][0], c1, 0, 0, 0);
        c2 = __builtin_amdgcn_mfma_f32_16x16x32_bf16(a0, b[2][0], c2, 0, 0, 0);
        c3 = __builtin_amdgcn_mfma_f32_16x16x32_bf16(a0, b[3][0], c3, 0, 0, 0);
        c0 = __builtin_amdgcn_mfma_f32_16x16x32_bf16(a1, b[0][1], c0, 0, 0, 0);
        c1 = __builtin_amdgcn_mfma_f32_16x16x32_bf16(a1, b[1][1], c1, 0, 0, 0);
        c2 = __builtin_amdgcn_mfma_f32_16x16x32_bf16(a1, b[2][1], c2, 0, 0, 0);
        c3 = __builtin_amdgcn_mfma_f32_16x16x32_bf16(a1, b[3][1], c3, 0, 0, 0);

        const int e_base = k * M + t * 16;
        f32x4 cc[4] = {c0, c1, c2, c3};
#pragma unroll
        for (int r = 0; r < 4; ++r) {
            int row = lg * 4 + r;
            if (t * 16 + row < M) {
                int p = inv[e_base + row];            // broadcast within l15-group
                __bf16* cr = C + (size_t)p * 64 + l15;
#pragma unroll
                for (int nt = 0; nt < 4; ++nt) {
                    __bf16 v = (__bf16)cc[nt][r];
                    __builtin_nontemporal_store(v, cr + nt * 16);
                }
            }
        }
    }
}

// ===========================================================================
// Phase B: segmented streaming reduce + FUSED GroupNorm stats. One wave per
// output row per iter; 8 rows/instruction: lane = (row l>>3) x (channel
// octet l&7), dwordx4 load = 1KB/wave-instruction. Channel octet == GN
// group. Output is bf16 (19MB).
// ===========================================================================
__global__ __launch_bounds__(256) void reduce_kernel(
    const uintx4* __restrict__ C4, const int* __restrict__ base,
    __bf16* __restrict__ out, float* __restrict__ stats, int N)
{
    const int lane = threadIdx.x & 63;
    const int wv   = threadIdx.x >> 6;
    const int ro   = lane >> 3;       // row offset 0..7
    const int oc   = lane & 7;        // channel octet == GN group
    float rs = 0.f, rq = 0.f;

    const int ostride = gridDim.x * 4;
    for (int o = blockIdx.x * 4 + wv; o < N; o += ostride) {
        const int s = base[o], t = base[o + 1];
        float a0 = 0.f, a1 = 0.f, a2 = 0.f, a3 = 0.f;
        float a4 = 0.f, a5 = 0.f, a6 = 0.f, a7 = 0.f;
        for (int i = s + ro; i < t; i += 8) {
            uintx4 v = __builtin_nontemporal_load(&C4[(size_t)i * 8 + oc]);
            a0 += bf_lo(v.x); a1 += bf_hi(v.x);
            a2 += bf_lo(v.y); a3 += bf_hi(v.y);
            a4 += bf_lo(v.z); a5 += bf_hi(v.z);
            a6 += bf_lo(v.w); a7 += bf_hi(v.w);
        }
#pragma unroll
        for (int m = 8; m <= 32; m <<= 1) {
            a0 += __shfl_xor(a0, m); a1 += __shfl_xor(a1, m);
            a2 += __shfl_xor(a2, m); a3 += __shfl_xor(a3, m);
            a4 += __shfl_xor(a4, m); a5 += __shfl_xor(a5, m);
            a6 += __shfl_xor(a6, m); a7 += __shfl_xor(a7, m);
        }
        if (ro == 0) {
            bf16x8 r;
            r[0] = (__bf16)a0; r[1] = (__bf16)a1; r[2] = (__bf16)a2; r[3] = (__bf16)a3;
            r[4] = (__bf16)a4; r[5] = (__bf16)a5; r[6] = (__bf16)a6; r[7] = (__bf16)a7;
            *(bf16x8*)(out + (size_t)o * 64 + oc * 8) = r;
            rs += ((a0 + a1) + (a2 + a3)) + ((a4 + a5) + (a6 + a7));
            rq += ((a0*a0 + a1*a1) + (a2*a2 + a3*a3)) + ((a4*a4 + a5*a5) + (a6*a6 + a7*a7));
        }
    }
    __shared__ float ls[4][16];
    if (ro == 0) { ls[wv][oc] = rs; ls[wv][8 + oc] = rq; }
    __syncthreads();
    if (threadIdx.x < 16) {
        float t = (ls[0][threadIdx.x] + ls[1][threadIdx.x]) +
                  (ls[2][threadIdx.x] + ls[3][threadIdx.x]);
        unsafeAtomicAdd(stats + threadIdx.x, t);
    }
}

// ===========================================================================
// GroupNorm apply (+residual, +leaky). BFIN: main input bf16 or fp32.
// RBF: residual bf16 (main path keeps residual chain in bf16; one extra
// rounding of h, absmax headroom 0.2075 >> 0.125) or fp32 (fallback).
// ===========================================================================
template<int BFIN, int RBF>
__global__ __launch_bounds__(256) void gn_apply_kernel(
    const void* __restrict__ xin, const float* __restrict__ stats,
    const float* __restrict__ gamma, const float* __restrict__ beta,
    const void* resid, float4* out_f, bf16x4* out_bf,
    long total4, float invc, int do_leaky)
{
    __shared__ float sc[64], sh[64];
    if (threadIdx.x < 64) {
        int c = threadIdx.x, g = c >> 3;
        float mean = stats[g] * invc;
        float var  = fmaf(-mean, mean, stats[8 + g] * invc);
        float s    = rsqrtf(var + GN_EPS) * gamma[c];
        sc[c] = s;
        sh[c] = fmaf(-mean, s, beta[c]);
    }
    __syncthreads();
    const long stride = (long)gridDim.x * blockDim.x;
    for (long i = (long)blockIdx.x * blockDim.x + threadIdx.x; i < total4; i += stride) {
        float4 v;
        if (BFIN) {
            bf16x4 u = ((const bf16x4*)xin)[i];
            v.x = (float)u.x; v.y = (float)u.y; v.z = (float)u.z; v.w = (float)u.w;
        } else {
            v = ((const float4*)xin)[i];
        }
        int c0 = ((int)(i & 15)) << 2;
        float4 r;
        r.x = fmaf(v.x, sc[c0 + 0], sh[c0 + 0]);
        r.y = fmaf(v.y, sc[c0 + 1], sh[c0 + 1]);
        r.z = fmaf(v.z, sc[c0 + 2], sh[c0 + 2]);
        r.w = fmaf(v.w, sc[c0 + 3], sh[c0 + 3]);
        if (resid) {
            float4 h4;
            if (RBF) {
                bf16x4 u = ((const bf16x4*)resid)[i];
                h4.x = (float)u.x; h4.y = (float)u.y; h4.z = (float)u.z; h4.w = (float)u.w;
            } else {
                h4 = ((const float4*)resid)[i];
            }
            r.x += h4.x; r.y += h4.y; r.z += h4.z; r.w += h4.w;
        }
        if (do_leaky) {
            r.x = r.x >= 0.f ? r.x : NEG_SLOPE * r.x;
            r.y = r.y >= 0.f ? r.y : NEG_SLOPE * r.y;
            r.z = r.z >= 0.f ? r.z : NEG_SLOPE * r.z;
            r.w = r.w >= 0.f ? r.w : NEG_SLOPE * r.w;
        }
        if (out_f) out_f[i] = r;
        if (out_bf) {
            bf16x4 o;
            o.x = (__bf16)r.x; o.y = (__bf16)r.y; o.z = (__bf16)r.z; o.w = (__bf16)r.w;
            out_bf[i] = o;
        }
    }
}

// ===========================================================================
// Legacy atomic-scatter conv + standalone gn_stats (ws_size fallback path)
// ===========================================================================
__global__ __launch_bounds__(256) void conv_kernel(
    const float* __restrict__ feats, const float* __restrict__ W,
    const int* __restrict__ in_map, const int* __restrict__ out_map,
    float* __restrict__ out, int M, int BPK)
{
    const int lane = threadIdx.x & 63;
    const int wv   = threadIdx.x >> 6;
    const int k    = blockIdx.x / BPK;
    const int blk  = blockIdx.x % BPK;
    const float* Wk = W + (size_t)k * 4096;
    float w[64];
#pragma unroll
    for (int c = 0; c < 64; ++c) w[c] = Wk[c * 64 + lane];
    __shared__ float fbuf[4][64];
    const int* im = in_map + (size_t)k * M;
    const int* om = out_map + (size_t)k * M;
    const int stride = BPK * 4;
    for (int m = blk * 4 + wv; m < M; m += stride) {
        int ii = im[m];
        int oi = om[m];
        float f = feats[(size_t)ii * 64 + lane];
        fbuf[wv][lane] = f;
        const float* fb = fbuf[wv];
        float a0 = 0.f, a1 = 0.f, a2 = 0.f, a3 = 0.f;
#pragma unroll
        for (int c = 0; c < 64; c += 4) {
            float4 f4 = *(const float4*)(fb + c);
            a0 = fmaf(f4.x, w[c + 0], a0);
            a1 = fmaf(f4.y, w[c + 1], a1);
            a2 = fmaf(f4.z, w[c + 2], a2);
            a3 = fmaf(f4.w, w[c + 3], a3);
        }
        unsafeAtomicAdd(out + (size_t)oi * 64 + lane, (a0 + a1) + (a2 + a3));
    }
}

__global__ __launch_bounds__(256) void gn_stats_kernel(
    const float4* __restrict__ x, float* __restrict__ stats, long total4)
{
    const int lane = threadIdx.x & 63;
    float s = 0.f, q = 0.f;
    const long stride = (long)gridDim.x * blockDim.x;
    for (long i = (long)blockIdx.x * blockDim.x + threadIdx.x; i < total4; i += stride) {
        float4 v = x[i];
        s += (v.x + v.y) + (v.z + v.w);
        q += (v.x * v.x + v.y * v.y) + (v.z * v.z + v.w * v.w);
    }
    s += __shfl_xor(s, 1);  q += __shfl_xor(q, 1);
    s += __shfl_xor(s, 16); q += __shfl_xor(q, 16);
    s += __shfl_xor(s, 32); q += __shfl_xor(q, 32);
    __shared__ float ls[4][16];
    const int wv = threadIdx.x >> 6;
    const int g = (lane >> 1) & 7;
    if (lane < 16 && (lane & 1) == 0) { ls[wv][g] = s; ls[wv][8 + g] = q; }
    __syncthreads();
    if (threadIdx.x < 16) {
        float t = (ls[0][threadIdx.x] + ls[1][threadIdx.x]) +
                  (ls[2][threadIdx.x] + ls[3][threadIdx.x]);
        unsafeAtomicAdd(stats + threadIdx.x, t);
    }
}

// ===========================================================================
extern "C" void kernel_launch(void* const* d_in, const int* in_sizes, int n_in,
                              void* d_out, int out_size, void* d_ws, size_t ws_size,
                              hipStream_t stream) {
    const float* x   = (const float*)d_in[0];
    const float* W1  = (const float*)d_in[1];
    const float* g1  = (const float*)d_in[2];
    const float* b1  = (const float*)d_in[3];
    const float* Wa1 = (const float*)d_in[4];
    const float* ga1 = (const float*)d_in[5];
    const float* ba1 = (const float*)d_in[6];
    const float* Wb1 = (const float*)d_in[7];
    const float* gb1 = (const float*)d_in[8];
    const float* bb1 = (const float*)d_in[9];
    const float* Wa2 = (const float*)d_in[10];
    const float* ga2 = (const float*)d_in[11];
    const float* ba2 = (const float*)d_in[12];
    const float* Wb2 = (const float*)d_in[13];
    const float* gb2 = (const float*)d_in[14];
    const float* bb2 = (const float*)d_in[15];
    const int* m1_in  = (const int*)d_in[16];
    const int* m1_out = (const int*)d_in[17];
    const int* m2_in  = (const int*)d_in[18];
    const int* m2_out = (const int*)d_in[19];

    const int N   = out_size / 64;
    const int M1  = in_sizes[16] / 8;
    const int M2  = in_sizes[18] / 27;
    const int E1  = 8 * M1;
    const int E2  = 27 * M2;
    const int Emax = E1 > E2 ? E1 : E2;

    float* h = (float*)d_out;
    const long  total4 = (long)N * 16;
    const float invc   = 1.f / ((float)N * 8.f);

    // ---- workspace layout (256B aligned) ----
    char* wp = (char*)d_ws;
    size_t off = 0;
    auto alloc = [&](size_t bytes) {
        void* p = wp + off;
        off = (off + bytes + 255) & ~(size_t)255;
        return p;
    };
    __bf16* accbf = (__bf16*)alloc((size_t)N * 64 * 2);
    __bf16* hbf   = (__bf16*)alloc((size_t)N * 64 * 2);
    __bf16* ybf   = (__bf16*)alloc((size_t)N * 64 * 2);
    __bf16* Cbuf  = (__bf16*)alloc((size_t)Emax * 64 * 2);
    int*    base1 = (int*)alloc((size_t)(N + 1) * 4);
    int*    base2 = (int*)alloc((size_t)(N + 1) * 4);
    int*    cnt   = (int*)alloc((size_t)N * 4);
    int*    part  = (int*)alloc(4096);
    int*    inv1  = (int*)alloc((size_t)E1 * 4);
    int*    inv2  = (int*)alloc((size_t)E2 * 4);
    float*  stats = (float*)alloc(5 * 16 * 4);   // st0, stA1, stB1, stA2, stB2
    const size_t need = off;

    if (ws_size < need) {
        // -------- legacy atomic fallback (independent fp32 layout) --------
        float* accF = (float*)d_ws;
        float* yF   = accF + (size_t)N * 64;
        float* stF  = yF + (size_t)N * 64;
        const size_t nbytes = (size_t)N * 64 * 4;
        auto convL = [&](const float* feats, const float* W, const int* im,
                         const int* om, int K, int M, int BPK) {
            hipMemsetAsync(accF, 0, nbytes, stream);
            conv_kernel<<<dim3(K * BPK), 256, 0, stream>>>(feats, W, im, om, accF, M, BPK);
        };
        auto gnL = [&](const float* gamma, const float* beta, const float* resid,
                       float* outp, int leaky) {
            hipMemsetAsync(stF, 0, 16 * sizeof(float), stream);
            gn_stats_kernel<<<1024, 256, 0, stream>>>((const float4*)accF, stF, total4);
            gn_apply_kernel<0, 0><<<1024, 256, 0, stream>>>(accF, stF, gamma, beta,
                                                            resid, (float4*)outp,
                                                            nullptr, total4, invc, leaky);
        };
        convL(x, W1, m1_in, m1_out, 8, M1, 320); gnL(g1, b1, nullptr, h, 1);
        convL(h, Wa1, m2_in, m2_out, 27, M2, 96); gnL(ga1, ba1, nullptr, yF, 0);
        convL(yF, Wb1, m2_in, m2_out, 27, M2, 96); gnL(gb1, bb1, h, h, 1);
        convL(h, Wa2, m2_in, m2_out, 27, M2, 96); gnL(ga2, ba2, nullptr, yF, 0);
        convL(yF, Wb2, m2_in, m2_out, 27, M2, 96); gnL(gb2, bb2, h, h, 1);
        return;
    }

    // -------- MFMA + sorted-streaming-reduce path (r15 proven) --------
    hipMemsetAsync(stats, 0, 5 * 16 * sizeof(float), stream);

    const int nb = (N + 1023) / 1024;
    auto buildCSR = [&](const int* om, int E, int* base, int* inv) {
        hipMemsetAsync(cnt, 0, (size_t)N * 4, stream);
        hist_kernel<<<2048, 256, 0, stream>>>(om, cnt, E);
        scan1_kernel<<<nb, 256, 0, stream>>>(cnt, part, N);
        scan2_kernel<<<1, 64, 0, stream>>>(part, nb);
        scan3_kernel<<<nb, 256, 0, stream>>>(cnt, part, base, N);
        hipMemsetAsync(cnt, 0, (size_t)N * 4, stream);
        scatter_kernel<<<2048, 256, 0, stream>>>(om, base, cnt, inv, E);
    };
    buildCSR(m1_out, E1, base1, inv1);
    buildCSR(m2_out, E2, base2, inv2);

    float* st0  = stats;
    float* stA1 = stats + 16;
    float* stB1 = stats + 32;
    float* stA2 = stats + 48;
    float* stB2 = stats + 64;

    auto conv = [&](const void* feats, int f32in, const float* W, const int* im,
                    int K, int M, int BPK, const int* base, const int* inv,
                    float* statOut) {
        dim3 grid(K * BPK);
        if (f32in)
            conv_mfma_kernel<1><<<grid, 256, 0, stream>>>(feats, W, im, inv, Cbuf, M, BPK);
        else
            conv_mfma_kernel<0><<<grid, 256, 0, stream>>>(feats, W, im, inv, Cbuf, M, BPK);
        reduce_kernel<<<2048, 256, 0, stream>>>((const uintx4*)Cbuf, base,
                                                accbf, statOut, N);
    };
    // bf16-residual gn apply: resid is bf16 (hbf), outputs fp32 and/or bf16
    auto gn = [&](const float* st, const float* gamma, const float* beta,
                  const __bf16* resid, float* outf, __bf16* outbf, int leaky) {
        gn_apply_kernel<1, 1><<<2048, 256, 0, stream>>>(accbf, st, gamma, beta,
                                                        resid, (float4*)outf,
                                                        (bf16x4*)outbf, total4, invc, leaky);
    };

    // BasicConvolutionBlock (gathers fp32 x directly); h kept in bf16 (hbf)
    conv(x, 1, W1, m1_in, 8, M1, 256, base1, inv1, st0);
    gn(st0, g1, b1, nullptr, nullptr, hbf, 1);
    // ResidualBlock 1
    conv(hbf, 0, Wa1, m2_in, 27, M2, 96, base2, inv2, stA1);
    gn(stA1, ga1, ba1, nullptr, nullptr, ybf, 0);
    conv(ybf, 0, Wb1, m2_in, 27, M2, 96, base2, inv2, stB1);
    gn(stB1, gb1, bb1, hbf, nullptr, hbf, 1);      // resid=hbf, out hbf (in-place)
    // ResidualBlock 2
    conv(hbf, 0, Wa2, m2_in, 27, M2, 96, base2, inv2, stA2);
    gn(stA2, ga2, ba2, nullptr, nullptr, ybf, 0);
    conv(ybf, 0, Wb2, m2_in, 27, M2, 96, base2, inv2, stB2);
    gn(stB2, gb2, bb2, hbf, h, nullptr, 1);        // final fp32 output
}